// Round 2
// baseline (5470.540 us; speedup 1.0000x reference)
//
#include <hip/hip_runtime.h>

// ---------------------------------------------------------------------------
// Bidirectional 2-layer LSTM + MLP head for B=512, T=1024, F=8, H1=70, H2=21.
//
// R2 change: batch-sliced pipeline, slice count chosen from ws_size at launch
// (deterministic per session -> graph-safe). R1 wrote ~368 MiB into d_ws
// without checking ws_size -> presumed OOB -> GPU memory fault -> abort.
// Now peak usage = wp(0.2MB) + h1_slice + pre2_slice; h2 aliases dead h1.
//   n=1: 320 MiB, n=2: 160, n=4: 80, n=8: 40, n=16: 20, n=32: 10.7.
// ---------------------------------------------------------------------------

typedef _Float16 v2f16 __attribute__((ext_vector_type(2)));
typedef _Float16 v4h   __attribute__((ext_vector_type(4)));
typedef _Float16 v8h   __attribute__((ext_vector_type(8)));

__device__ __forceinline__ float fdot2(v2f16 a, v2f16 b, float c) {
#if __has_builtin(__builtin_amdgcn_fdot2)
  return __builtin_amdgcn_fdot2(a, b, c, false);
#else
  return c + (float)a[0] * (float)b[0] + (float)a[1] * (float)b[1];
#endif
}

__device__ __forceinline__ float sigm(float v) {
  v = fminf(fmaxf(v, -30.f), 30.f);
  return 1.f / (1.f + __expf(-v));
}
__device__ __forceinline__ float tanh_(float v) {
  v = fminf(fmaxf(v, -15.f), 15.f);
  float e = __expf(-2.f * v);
  return (1.f - e) / (1.f + e);
}

// ---------------------------------------------------------------------------
// K0: pack weights to fp16.
// wp1[d][280][80] : k<8 = w_ih1[r][k], 8<=k<78 = w_hh1[r][k-8], else 0
// wp2[d][84][24]  : k<21 = w_hh2[r][k], else 0
// ---------------------------------------------------------------------------
__global__ void pack_kernel(const float* __restrict__ wihf, const float* __restrict__ whhf,
                            const float* __restrict__ wihb, const float* __restrict__ whhb,
                            const float* __restrict__ whh2f, const float* __restrict__ whh2b,
                            _Float16* __restrict__ wp1, _Float16* __restrict__ wp2) {
  int idx = blockIdx.x * 256 + threadIdx.x;
  if (idx < 44800) {
    int d = idx / 22400, rem = idx % 22400, r = rem / 80, k = rem % 80;
    const float* wih = d ? wihb : wihf;
    const float* whh = d ? whhb : whhf;
    float v = 0.f;
    if (k < 8) v = wih[r * 8 + k];
    else if (k < 78) v = whh[r * 70 + (k - 8)];
    wp1[idx] = (_Float16)v;
  } else {
    int j = idx - 44800;
    if (j < 4032) {
      int d = j / 2016, rem = j % 2016, r = rem / 24, k = rem % 24;
      const float* whh = d ? whh2b : whh2f;
      float v = (k < 21) ? whh[r * 21 + k] : 0.f;
      wp2[j] = (_Float16)v;
    }
  }
}

// ---------------------------------------------------------------------------
// K1: layer-1 BiLSTM for one batch slice. grid (nbp, 2 dirs), block 192
// (140 active). gp0 = global batch-pair offset of this slice.
// ---------------------------------------------------------------------------
__global__ __launch_bounds__(192, 2) void lstm1_kernel(
    const float* __restrict__ x,
    const float* __restrict__ bih_f, const float* __restrict__ bhh_f,
    const float* __restrict__ bih_b, const float* __restrict__ bhh_b,
    const _Float16* __restrict__ wp1,
    _Float16* __restrict__ h1g, int gp0, int nbp) {
  __shared__ _Float16 kvec[2][2][80];  // [buf][b01][ 0..7 x | 8..77 h | pad ]
  const int tid = threadIdx.x;
  const int bp = blockIdx.x;
  const int gp = gp0 + bp;
  const int d = blockIdx.y;
  const bool active = tid < 140;
  const int u = tid >> 1, b01 = tid & 1;
  const bool loader = (tid >= 140 && tid < 156);
  const int lj = tid - 140, lb = lj >> 3, lk = lj & 7;

  for (int i = tid; i < 2 * 2 * 80; i += 192) ((_Float16*)kvec)[i] = (_Float16)0.f;

  v2f16 wgt[4][40];
  float bias[4];
  float c = 0.f;
  if (active) {
    const float* bih = d ? bih_b : bih_f;
    const float* bhh = d ? bhh_b : bhh_f;
#pragma unroll
    for (int g = 0; g < 4; ++g) {
      int r = g * 70 + u;
      bias[g] = bih[r] + bhh[r];
      const v8h* wrow = (const v8h*)&wp1[(d * 280 + r) * 80];
#pragma unroll
      for (int ch = 0; ch < 10; ++ch) {
        v8h wv = wrow[ch];
#pragma unroll
        for (int p = 0; p < 4; ++p) {
          v2f16 t;
          t[0] = wv[2 * p];
          t[1] = wv[2 * p + 1];
          wgt[g][ch * 4 + p] = t;
        }
      }
    }
  }
  if (loader) {
    int t0 = d ? 1023 : 0;
    kvec[0][lb][lk] = (_Float16)x[((gp * 2 + lb) * 1024 + t0) * 8 + lk];
  }
  __syncthreads();

#pragma unroll 1
  for (int s = 0; s < 1024; ++s) {
    const int cur = s & 1, nxt = cur ^ 1;
    if (loader && s < 1023) {
      int tn = d ? (1022 - s) : (s + 1);
      kvec[nxt][lb][lk] = (_Float16)x[((gp * 2 + lb) * 1024 + tn) * 8 + lk];
    }
    if (active) {
      float acc[4] = {bias[0], bias[1], bias[2], bias[3]};
      const float4* kp = (const float4*)&kvec[cur][b01][0];
#pragma unroll
      for (int ch = 0; ch < 10; ++ch) {
        float4 q = kp[ch];
        v2f16 kk[4] = {__builtin_bit_cast(v2f16, q.x), __builtin_bit_cast(v2f16, q.y),
                       __builtin_bit_cast(v2f16, q.z), __builtin_bit_cast(v2f16, q.w)};
#pragma unroll
        for (int g = 0; g < 4; ++g) {
#pragma unroll
          for (int p = 0; p < 4; ++p) acc[g] = fdot2(kk[p], wgt[g][ch * 4 + p], acc[g]);
        }
      }
      float is = sigm(acc[0]);
      float fs = sigm(acc[1]);
      float gt = tanh_(acc[2]);
      float os = sigm(acc[3]);
      c = fs * c + is * gt;
      float hv = os * tanh_(c);
      int te = d ? (1023 - s) : s;
      h1g[(size_t)((te * nbp + bp) * 2 + b01) * 144 + d * 70 + u] = (_Float16)hv;
      kvec[nxt][b01][8 + u] = (_Float16)hv;
    }
    __syncthreads();
  }
}

// ---------------------------------------------------------------------------
// K2: pre2 GEMM. C[rows x 168] = A[rows x 140(fp16)] * Wcat^T + biases.
// ---------------------------------------------------------------------------
__global__ __launch_bounds__(128, 4) void pre2_kernel(
    const _Float16* __restrict__ h1g,
    const float* __restrict__ wf, const float* __restrict__ wb,
    const float* __restrict__ bif, const float* __restrict__ bhf,
    const float* __restrict__ bib, const float* __restrict__ bhb,
    _Float16* __restrict__ pre2) {
  __shared__ _Float16 At[128][152];
  const int tid = threadIdx.x;
  const int r0 = blockIdx.x * 128;
#pragma unroll 1
  for (int i = 0; i < 18; ++i) {
    int cid = i * 128 + tid;
    int row = cid / 18, cc = cid % 18;
    *(v8h*)&At[row][cc * 8] = *(const v8h*)&h1g[(size_t)(r0 + row) * 144 + cc * 8];
  }
  __syncthreads();
#pragma unroll 1
  for (int cg = 0; cg < 6; ++cg) {
    const float* wp = (cg < 3) ? wf : wb;
    const float* bi = (cg < 3) ? bif : bib;
    const float* bh = (cg < 3) ? bhf : bhb;
    int rb = ((cg < 3) ? cg : cg - 3) * 28;
    float acc[28];
#pragma unroll
    for (int cc = 0; cc < 28; ++cc) acc[cc] = bi[rb + cc] + bh[rb + cc];
#pragma unroll 1
    for (int kk = 0; kk < 140; kk += 4) {
      v4h a = *(const v4h*)&At[tid][kk];
      float a0 = (float)a[0], a1 = (float)a[1], a2 = (float)a[2], a3 = (float)a[3];
#pragma unroll
      for (int cc = 0; cc < 28; ++cc) {
        const float* wr = &wp[(rb + cc) * 140 + kk];
        acc[cc] += a0 * wr[0] + a1 * wr[1] + a2 * wr[2] + a3 * wr[3];
      }
    }
    _Float16* op = &pre2[(size_t)(r0 + tid) * 176 + cg * 28];
#pragma unroll
    for (int cc = 0; cc < 28; ++cc) op[cc] = (_Float16)acc[cc];
  }
}

// ---------------------------------------------------------------------------
// K3: layer-2 recurrence for one slice. grid nbp, block 128 (84 active).
// ---------------------------------------------------------------------------
__global__ __launch_bounds__(128, 4) void lstm2_kernel(
    const _Float16* __restrict__ pre2,
    const _Float16* __restrict__ wp2,
    _Float16* __restrict__ h2g, int nbp) {
  __shared__ _Float16 kv2[2][2][2][24];
  const int tid = threadIdx.x;
  const int bp = blockIdx.x;
  const bool active = tid < 84;
  const int d = tid / 42, rr = tid % 42, b01 = rr / 21, u = rr % 21;
  const bool padw = (tid >= 84 && tid < 96);
  const int pj = tid - 84, pb = pj / 6, pk = 42 + pj % 6;

  for (int i = tid; i < 2 * 2 * 2 * 24; i += 128) ((_Float16*)kv2)[i] = (_Float16)0.f;

  v2f16 wgt[4][12];
  float c = 0.f;
  if (active) {
#pragma unroll
    for (int g = 0; g < 4; ++g) {
      const v8h* wrow = (const v8h*)&wp2[(d * 84 + g * 21 + u) * 24];
#pragma unroll
      for (int ch = 0; ch < 3; ++ch) {
        v8h wv = wrow[ch];
#pragma unroll
        for (int p = 0; p < 4; ++p) {
          v2f16 t;
          t[0] = wv[2 * p];
          t[1] = wv[2 * p + 1];
          wgt[g][ch * 4 + p] = t;
        }
      }
    }
  }
  __syncthreads();

#pragma unroll 1
  for (int s = 0; s < 1024; ++s) {
    const int cur = s & 1, nxt = cur ^ 1;
    if (active) {
      int te = d ? (1023 - s) : s;
      size_t rowb = (size_t)((te * nbp + bp) * 2 + b01);
      const _Float16* pp = &pre2[rowb * 176 + d * 84 + u];
      float acc[4];
#pragma unroll
      for (int g = 0; g < 4; ++g) acc[g] = (float)pp[21 * g];
      const float4* kp = (const float4*)&kv2[cur][d][b01][0];
#pragma unroll
      for (int ch = 0; ch < 3; ++ch) {
        float4 q = kp[ch];
        v2f16 kk[4] = {__builtin_bit_cast(v2f16, q.x), __builtin_bit_cast(v2f16, q.y),
                       __builtin_bit_cast(v2f16, q.z), __builtin_bit_cast(v2f16, q.w)};
#pragma unroll
        for (int g = 0; g < 4; ++g) {
#pragma unroll
          for (int p = 0; p < 4; ++p) acc[g] = fdot2(kk[p], wgt[g][ch * 4 + p], acc[g]);
        }
      }
      float is = sigm(acc[0]);
      float fs = sigm(acc[1]);
      float gt = tanh_(acc[2]);
      float os = sigm(acc[3]);
      c = fs * c + is * gt;
      float hv = os * tanh_(c);
      h2g[rowb * 48 + d * 21 + u] = (_Float16)hv;
      kv2[nxt][d][b01][u] = (_Float16)hv;
    }
    if (padw) {
      size_t rowb = (size_t)((s * nbp + bp) * 2 + pb);
      h2g[rowb * 48 + pk] = (_Float16)0.f;
    }
    __syncthreads();
  }
}

// ---------------------------------------------------------------------------
// K4: dense head for one slice.
// ---------------------------------------------------------------------------
__global__ __launch_bounds__(256, 2) void head_kernel(
    const _Float16* __restrict__ h2g,
    const float* __restrict__ d1w, const float* __restrict__ d1b,
    const float* __restrict__ d2w, const float* __restrict__ d2b,
    const float* __restrict__ ow, const float* __restrict__ ob,
    float* __restrict__ out, int b0, int nbp) {
  int n = blockIdx.x * 256 + threadIdx.x;
  int t = n & 1023, bl = n >> 10;
  size_t row = (size_t)((t * nbp + (bl >> 1)) * 2 + (bl & 1));
  const v8h* hp = (const v8h*)&h2g[row * 48];
  float in[48];
#pragma unroll
  for (int i = 0; i < 6; ++i) {
    v8h hc = hp[i];
#pragma unroll
    for (int j = 0; j < 8; ++j) in[i * 8 + j] = (float)hc[j];
  }
  float a1[30];
#pragma unroll
  for (int cc = 0; cc < 30; ++cc) {
    float a = d1b[cc];
#pragma unroll
    for (int k = 0; k < 42; ++k) a += in[k] * d1w[cc * 42 + k];
    a1[cc] = fmaxf(a, 0.f);
  }
  float a2[20];
#pragma unroll
  for (int cc = 0; cc < 20; ++cc) {
    float a = d2b[cc];
#pragma unroll
    for (int k = 0; k < 30; ++k) a += a1[k] * d2w[cc * 30 + k];
    a2[cc] = fmaxf(a, 0.f);
  }
  float o = ob[0];
#pragma unroll
  for (int k = 0; k < 20; ++k) o += a2[k] * ow[k];
  out[(size_t)(b0 + bl) * 1024 + t] = o;
}

// ---------------------------------------------------------------------------
extern "C" void kernel_launch(void* const* d_in, const int* in_sizes, int n_in,
                              void* d_out, int out_size, void* d_ws, size_t ws_size,
                              hipStream_t stream) {
  const float* x = (const float*)d_in[0];
  const float* wih1f = (const float*)d_in[1];
  const float* whh1f = (const float*)d_in[2];
  const float* bih1f = (const float*)d_in[3];
  const float* bhh1f = (const float*)d_in[4];
  const float* wih1b = (const float*)d_in[5];
  const float* whh1b = (const float*)d_in[6];
  const float* bih1b = (const float*)d_in[7];
  const float* bhh1b = (const float*)d_in[8];
  const float* wih2f = (const float*)d_in[9];
  const float* whh2f = (const float*)d_in[10];
  const float* bih2f = (const float*)d_in[11];
  const float* bhh2f = (const float*)d_in[12];
  const float* wih2b = (const float*)d_in[13];
  const float* whh2b = (const float*)d_in[14];
  const float* bih2b = (const float*)d_in[15];
  const float* bhh2b = (const float*)d_in[16];
  const float* d1w = (const float*)d_in[17];
  const float* d1b = (const float*)d_in[18];
  const float* d2w = (const float*)d_in[19];
  const float* d2b = (const float*)d_in[20];
  const float* ow = (const float*)d_in[21];
  const float* ob = (const float*)d_in[22];
  float* out = (float*)d_out;

  const size_t WP1B = 179200, WP2B = 8064;
  const size_t data0 = WP1B + WP2B;  // 187264, 16B aligned
  const int cands[6] = {1, 2, 4, 8, 16, 32};
  int nslice = 32;
  for (int i = 0; i < 6; ++i) {
    int n = cands[i];
    size_t h1b_n = (size_t)(512 / n) * 1024 * 288;
    size_t p2b_n = (size_t)(512 / n) * 1024 * 352;
    if (data0 + h1b_n + p2b_n <= ws_size) { nslice = n; break; }
  }
  const int nb = 512 / nslice;
  const int nbp = nb / 2;
  const size_t h1b = (size_t)nb * 1024 * 288;

  char* wsb = (char*)d_ws;
  _Float16* wp1  = (_Float16*)(wsb);
  _Float16* wp2  = (_Float16*)(wsb + WP1B);
  _Float16* h1g  = (_Float16*)(wsb + data0);
  _Float16* pre2 = (_Float16*)(wsb + data0 + h1b);
  _Float16* h2g  = h1g;  // alias: h1 dead once pre2 is built

  pack_kernel<<<191, 256, 0, stream>>>(wih1f, whh1f, wih1b, whh1b, whh2f, whh2b, wp1, wp2);

  for (int s = 0; s < nslice; ++s) {
    const int gp0 = s * nbp;
    const int b0 = s * nb;
    lstm1_kernel<<<dim3(nbp, 2), 192, 0, stream>>>(x, bih1f, bhh1f, bih1b, bhh1b,
                                                   wp1, h1g, gp0, nbp);
    pre2_kernel<<<nb * 8, 128, 0, stream>>>(h1g, wih2f, wih2b, bih2f, bhh2f,
                                            bih2b, bhh2b, pre2);
    lstm2_kernel<<<nbp, 128, 0, stream>>>(pre2, wp2, h2g, nbp);
    head_kernel<<<nb * 4, 256, 0, stream>>>(h2g, d1w, d1b, d2w, d2b, ow, ob, out, b0, nbp);
  }
}

// Round 3
// 4265.339 us; speedup vs baseline: 1.2826x; 1.2826x over previous
//
#include <hip/hip_runtime.h>

// ---------------------------------------------------------------------------
// BiLSTM(70) -> BiLSTM(21) -> MLP head. B=512 T=1024 F=8.
//
// R3: (1) pre2 GEMM on MFMA fp16 16x16x32, in-place over h1 (stride 176 fp16)
//     -> per-slice footprint 448 B/row -> nslice 4 if ws>=59MB (was 8).
//     (2) lstm1: 1 batch x 1 dir / block, thread=(gate,unit), shfl gate
//     combine, 4-way split accumulators. 256 blocks at nslice=4.
//     (3) lstm2: 1 batch x 1 dir / block, pre2 row prefetched 1 step ahead.
// ---------------------------------------------------------------------------

typedef _Float16 v2f16 __attribute__((ext_vector_type(2)));
typedef _Float16 v8h   __attribute__((ext_vector_type(8)));
typedef float    f32x4 __attribute__((ext_vector_type(4)));

__device__ __forceinline__ float fdot2(v2f16 a, v2f16 b, float c) {
  return __builtin_amdgcn_fdot2(a, b, c, false);
}
__device__ __forceinline__ float sigm(float v) {
  v = fminf(fmaxf(v, -30.f), 30.f);
  return 1.f / (1.f + __expf(-v));
}
__device__ __forceinline__ float tanh_(float v) {
  v = fminf(fmaxf(v, -15.f), 15.f);
  float e = __expf(-2.f * v);
  return (1.f - e) / (1.f + e);
}

// workspace offsets (bytes)
#define O_WP1  0u         // [2][280][80] fp16 = 89600
#define O_WP2  89600u     // [2][84][24]  fp16 = 8064
#define O_W2M  97664u     // [176][168]   fp16 = 59136 (pre2 B matrix, row=out col)
#define O_BIAS 156800u    // [176] f32    = 704
#define O_DATA 157504u    // h1/pre2 [rows][176] fp16, then h2 [rows][48] fp16

// ---------------------------------------------------------------------------
// K0: pack all weights.
// ---------------------------------------------------------------------------
__global__ void pack_kernel(const float* __restrict__ wihf, const float* __restrict__ whhf,
                            const float* __restrict__ wihb, const float* __restrict__ whhb,
                            const float* __restrict__ wih2f, const float* __restrict__ wih2b,
                            const float* __restrict__ whh2f, const float* __restrict__ whh2b,
                            const float* __restrict__ bif, const float* __restrict__ bhf,
                            const float* __restrict__ bib, const float* __restrict__ bhb,
                            char* __restrict__ ws) {
  _Float16* wp1 = (_Float16*)(ws + O_WP1);
  _Float16* wp2 = (_Float16*)(ws + O_WP2);
  _Float16* w2m = (_Float16*)(ws + O_W2M);
  float* biasc = (float*)(ws + O_BIAS);
  int idx = blockIdx.x * 256 + threadIdx.x;
  if (idx < 44800) {
    int d = idx / 22400, rem = idx % 22400, r = rem / 80, k = rem % 80;
    const float* wih = d ? wihb : wihf;
    const float* whh = d ? whhb : whhf;
    float v = 0.f;
    if (k < 8) v = wih[r * 8 + k];
    else if (k < 78) v = whh[r * 70 + (k - 8)];
    wp1[idx] = (_Float16)v;
  } else if (idx < 48832) {
    int j = idx - 44800;
    int d = j / 2016, rem = j % 2016, r = rem / 24, k = rem % 24;
    const float* whh = d ? whh2b : whh2f;
    wp2[j] = (_Float16)((k < 21) ? whh[r * 21 + k] : 0.f);
  } else if (idx < 78400) {
    int j = idx - 48832;  // < 29568
    int n = j / 168, k = j % 168;
    float v = 0.f;
    if (k < 140) {
      if (n < 84) v = wih2f[n * 140 + k];
      else if (n < 168) v = wih2b[(n - 84) * 140 + k];
    }
    w2m[j] = (_Float16)v;
  } else if (idx < 78576) {
    int n = idx - 78400;
    float v = 0.f;
    if (n < 84) v = bif[n] + bhf[n];
    else if (n < 168) v = bib[n - 84] + bhb[n - 84];
    biasc[n] = v;
  }
}

// ---------------------------------------------------------------------------
// K1: layer-1 LSTM, one (batch, dir) per block. block 320, active 280:
// tid = u*4+g. 40 fdot2/step/thread, gate quad combined via shfl_xor.
// h1 row = t*nb + bl, stride 176 fp16; writes cols d*70..+69; fwd blocks
// also zero K-pad cols 140..159 (read by pre2's K loop).
// ---------------------------------------------------------------------------
__global__ __launch_bounds__(320) void lstm1_kernel(
    const float* __restrict__ x,
    const float* __restrict__ bih_f, const float* __restrict__ bhh_f,
    const float* __restrict__ bih_b, const float* __restrict__ bhh_b,
    const _Float16* __restrict__ wp1,
    _Float16* __restrict__ h1, int b0, int nb) {
  __shared__ _Float16 kvec[2][80];  // [buf][ 0..7 x | 8..77 h | 78,79 zero ]
  const int tid = threadIdx.x;
  const int bl = blockIdx.x;      // slice-local batch
  const int gb = b0 + bl;         // global batch (for x)
  const int d = blockIdx.y;
  const bool active = tid < 280;
  const int u = tid >> 2, g = tid & 3;
  const bool loader = (tid >= 280 && tid < 288);
  const int lk = tid - 280;

  for (int i = tid; i < 160; i += 320) ((_Float16*)kvec)[i] = (_Float16)0.f;

  v2f16 wgt[40];
  float bias = 0.f, c = 0.f;
  if (active) {
    const float* bih = d ? bih_b : bih_f;
    const float* bhh = d ? bhh_b : bhh_f;
    int r = g * 70 + u;
    bias = bih[r] + bhh[r];
    const v8h* wrow = (const v8h*)&wp1[(d * 280 + r) * 80];
#pragma unroll
    for (int ch = 0; ch < 10; ++ch) {
      v8h wv = wrow[ch];
#pragma unroll
      for (int p = 0; p < 4; ++p) {
        v2f16 t; t[0] = wv[2 * p]; t[1] = wv[2 * p + 1];
        wgt[ch * 4 + p] = t;
      }
    }
  }
  if (loader) {
    int t0 = d ? 1023 : 0;
    kvec[0][lk] = (_Float16)x[(gb * 1024 + t0) * 8 + lk];
  }
  __syncthreads();

#pragma unroll 1
  for (int s = 0; s < 1024; ++s) {
    const int cur = s & 1, nxt = cur ^ 1;
    if (loader && s < 1023) {
      int tn = d ? (1022 - s) : (s + 1);
      kvec[nxt][lk] = (_Float16)x[(gb * 1024 + tn) * 8 + lk];
    }
    if (active) {
      float ac0 = bias, ac1 = 0.f, ac2 = 0.f, ac3 = 0.f;
      const float4* kp = (const float4*)&kvec[cur][0];
#pragma unroll
      for (int ch = 0; ch < 10; ++ch) {
        float4 q = kp[ch];
        ac0 = fdot2(__builtin_bit_cast(v2f16, q.x), wgt[ch * 4 + 0], ac0);
        ac1 = fdot2(__builtin_bit_cast(v2f16, q.y), wgt[ch * 4 + 1], ac1);
        ac2 = fdot2(__builtin_bit_cast(v2f16, q.z), wgt[ch * 4 + 2], ac2);
        ac3 = fdot2(__builtin_bit_cast(v2f16, q.w), wgt[ch * 4 + 3], ac3);
      }
      float a0 = (ac0 + ac1) + (ac2 + ac3);
      float a1 = __shfl_xor(a0, 1);
      float a2 = __shfl_xor(a0, 2);
      float a3 = __shfl_xor(a1, 2);
      // gate j's preact = a[g ^ j]
      float gi = (g == 0) ? a0 : (g == 1) ? a1 : (g == 2) ? a2 : a3;
      float gf = (g == 0) ? a1 : (g == 1) ? a0 : (g == 2) ? a3 : a2;
      float gg = (g == 0) ? a2 : (g == 1) ? a3 : (g == 2) ? a0 : a1;
      float go = (g == 0) ? a3 : (g == 1) ? a2 : (g == 2) ? a1 : a0;
      c = sigm(gf) * c + sigm(gi) * tanh_(gg);
      float hv = sigm(go) * tanh_(c);
      int te = d ? (1023 - s) : s;
      size_t row = (size_t)te * nb + bl;
      if (g == 0) {
        kvec[nxt][8 + u] = (_Float16)hv;
        h1[row * 176 + d * 70 + u] = (_Float16)hv;
      }
      if (d == 0 && g == 1 && u < 20) h1[row * 176 + 140 + u] = (_Float16)0.f;
    }
    __syncthreads();
  }
}

// ---------------------------------------------------------------------------
// K2: pre2 MFMA GEMM, in-place over h1. block 256 (4 waves), 64 rows/block.
// C[64][176] = A[64][K=160] * W^T + bias; A staged LDS (stride 184 breaks
// bank conflicts), B frags from global (L2-hot 59KB), next-ct prefetch.
// ---------------------------------------------------------------------------
__global__ __launch_bounds__(256) void pre2_kernel(
    _Float16* __restrict__ h1, const char* __restrict__ ws) {
  const _Float16* w2m = (const _Float16*)(ws + O_W2M);
  const float* biasc = (const float*)(ws + O_BIAS);
  __shared__ _Float16 Al[64][184];
  __shared__ float Bl[176];
  const int tid = threadIdx.x;
  const int r0 = blockIdx.x * 64;
  // stage A (64 rows x 176 cols = 1408 v8h)
#pragma unroll
  for (int i = 0; i < 6; ++i) {
    int cid = i * 256 + tid;
    if (cid < 1408) {
      int row = cid / 22, ch = cid % 22;
      *(v8h*)&Al[row][ch * 8] = *(const v8h*)&h1[(size_t)(r0 + row) * 176 + ch * 8];
    }
  }
  if (tid < 176) Bl[tid] = biasc[tid];
  __syncthreads();

  const int wv = tid >> 6, lane = tid & 63;
  const int ml = lane & 15, kq = lane >> 4;
  // A fragments (5 K-chunks of 32)
  v8h af[5];
#pragma unroll
  for (int k = 0; k < 5; ++k)
    af[k] = *(const v8h*)&Al[wv * 16 + ml][k * 32 + kq * 8];

  const v8h* wg = (const v8h*)w2m;  // row stride 21 v8h
  f32x4 acc[11];
#pragma unroll
  for (int ct = 0; ct < 11; ++ct) acc[ct] = (f32x4){0.f, 0.f, 0.f, 0.f};

  v8h bc[5], bn[5];
#pragma unroll
  for (int k = 0; k < 5; ++k) bn[k] = wg[(size_t)ml * 21 + k * 4 + kq];
#pragma unroll
  for (int ct = 0; ct < 11; ++ct) {
#pragma unroll
    for (int k = 0; k < 5; ++k) bc[k] = bn[k];
    if (ct < 10) {
#pragma unroll
      for (int k = 0; k < 5; ++k) bn[k] = wg[(size_t)((ct + 1) * 16 + ml) * 21 + k * 4 + kq];
    }
#pragma unroll
    for (int k = 0; k < 5; ++k)
      acc[ct] = __builtin_amdgcn_mfma_f32_16x16x32_f16(af[k], bc[k], acc[ct], 0, 0, 0);
  }
  __syncthreads();  // all waves done with Al frags
  // C -> Al (fp16, +bias), then coalesced flat store over h1
#pragma unroll
  for (int ct = 0; ct < 11; ++ct) {
#pragma unroll
    for (int r = 0; r < 4; ++r) {
      int row = wv * 16 + kq * 4 + r, col = ct * 16 + ml;
      Al[row][col] = (_Float16)(acc[ct][r] + Bl[col]);
    }
  }
  __syncthreads();
#pragma unroll
  for (int i = 0; i < 6; ++i) {
    int cid = i * 256 + tid;
    if (cid < 1408) {
      int row = cid / 22, ch = cid % 22;
      *(v8h*)&h1[(size_t)(r0 + row) * 176 + ch * 8] = *(const v8h*)&Al[row][ch * 8];
    }
  }
}

// ---------------------------------------------------------------------------
// K3: layer-2 LSTM, one (batch, dir) per block. block 128, active 84:
// tid = u*4+g (u<21). pre2 row value prefetched one step ahead.
// h2 row = t*nb+bl, stride 48 fp16; fwd cols 0..20, bwd 21..41, pad 42..47.
// ---------------------------------------------------------------------------
__global__ __launch_bounds__(128) void lstm2_kernel(
    const _Float16* __restrict__ pre2, const _Float16* __restrict__ wp2,
    _Float16* __restrict__ h2, int nb) {
  __shared__ _Float16 kv[2][24];
  const int tid = threadIdx.x;
  const int bl = blockIdx.x;
  const int d = blockIdx.y;
  const bool active = tid < 84;
  const int u = tid >> 2, g = tid & 3;

  for (int i = tid; i < 48; i += 128) ((_Float16*)kv)[i] = (_Float16)0.f;

  v2f16 wgt[12];
  float c = 0.f;
  int col = d * 84 + g * 21 + u;
  if (active) {
    const v8h* wrow = (const v8h*)&wp2[(d * 84 + g * 21 + u) * 24];
#pragma unroll
    for (int ch = 0; ch < 3; ++ch) {
      v8h wv = wrow[ch];
#pragma unroll
      for (int p = 0; p < 4; ++p) {
        v2f16 t; t[0] = wv[2 * p]; t[1] = wv[2 * p + 1];
        wgt[ch * 4 + p] = t;
      }
    }
  }
  __syncthreads();

  float pg = 0.f;
  if (active) {
    int t0 = d ? 1023 : 0;
    pg = (float)pre2[(size_t)(t0 * nb + bl) * 176 + col];
  }
#pragma unroll 1
  for (int s = 0; s < 1024; ++s) {
    const int cur = s & 1, nxt = cur ^ 1;
    _Float16 pn = (_Float16)0.f;
    if (active && s < 1023) {  // prefetch next step's preact
      int tn = d ? (1022 - s) : (s + 1);
      pn = pre2[(size_t)(tn * nb + bl) * 176 + col];
    }
    if (active) {
      float ac0 = pg, ac1 = 0.f, ac2 = 0.f;
      const float4* kp = (const float4*)&kv[cur][0];
#pragma unroll
      for (int ch = 0; ch < 3; ++ch) {
        float4 q = kp[ch];
        ac0 = fdot2(__builtin_bit_cast(v2f16, q.x), wgt[ch * 4 + 0], ac0);
        ac1 = fdot2(__builtin_bit_cast(v2f16, q.y), wgt[ch * 4 + 1], ac1);
        ac2 = fdot2(__builtin_bit_cast(v2f16, q.z), wgt[ch * 4 + 2], ac2);
        ac0 = fdot2(__builtin_bit_cast(v2f16, q.w), wgt[ch * 4 + 3], ac0);
      }
      float a0 = ac0 + ac1 + ac2;
      float a1 = __shfl_xor(a0, 1);
      float a2 = __shfl_xor(a0, 2);
      float a3 = __shfl_xor(a1, 2);
      float gi = (g == 0) ? a0 : (g == 1) ? a1 : (g == 2) ? a2 : a3;
      float gf = (g == 0) ? a1 : (g == 1) ? a0 : (g == 2) ? a3 : a2;
      float gg = (g == 0) ? a2 : (g == 1) ? a3 : (g == 2) ? a0 : a1;
      float go = (g == 0) ? a3 : (g == 1) ? a2 : (g == 2) ? a1 : a0;
      c = sigm(gf) * c + sigm(gi) * tanh_(gg);
      float hv = sigm(go) * tanh_(c);
      int te = d ? (1023 - s) : s;
      size_t row = (size_t)te * nb + bl;
      if (g == 0) {
        kv[nxt][u] = (_Float16)hv;
        h2[row * 48 + d * 21 + u] = (_Float16)hv;
      }
      if (d == 0 && g == 1 && u < 6) h2[row * 48 + 42 + u] = (_Float16)0.f;
      pg = (float)pn;
    }
    __syncthreads();
  }
}

// ---------------------------------------------------------------------------
// K4: dense head. local row = t*nb+bl -> out[(b0+bl)*1024 + t].
// ---------------------------------------------------------------------------
__global__ __launch_bounds__(256) void head_kernel(
    const _Float16* __restrict__ h2,
    const float* __restrict__ d1w, const float* __restrict__ d1b,
    const float* __restrict__ d2w, const float* __restrict__ d2b,
    const float* __restrict__ ow, const float* __restrict__ ob,
    float* __restrict__ out, int b0, int lognb) {
  int n = blockIdx.x * 256 + threadIdx.x;
  int t = n >> lognb, bl = n & ((1 << lognb) - 1);
  const v8h* hp = (const v8h*)&h2[(size_t)n * 48];
  float in[48];
#pragma unroll
  for (int i = 0; i < 6; ++i) {
    v8h hc = hp[i];
#pragma unroll
    for (int j = 0; j < 8; ++j) in[i * 8 + j] = (float)hc[j];
  }
  float a1[30];
#pragma unroll
  for (int cc = 0; cc < 30; ++cc) {
    float a = d1b[cc];
#pragma unroll
    for (int k = 0; k < 42; ++k) a += in[k] * d1w[cc * 42 + k];
    a1[cc] = fmaxf(a, 0.f);
  }
  float a2[20];
#pragma unroll
  for (int cc = 0; cc < 20; ++cc) {
    float a = d2b[cc];
#pragma unroll
    for (int k = 0; k < 30; ++k) a += a1[k] * d2w[cc * 30 + k];
    a2[cc] = fmaxf(a, 0.f);
  }
  float o = ob[0];
#pragma unroll
  for (int k = 0; k < 20; ++k) o += a2[k] * ow[k];
  out[(size_t)(b0 + bl) * 1024 + t] = o;
}

// ---------------------------------------------------------------------------
extern "C" void kernel_launch(void* const* d_in, const int* in_sizes, int n_in,
                              void* d_out, int out_size, void* d_ws, size_t ws_size,
                              hipStream_t stream) {
  const float* x = (const float*)d_in[0];
  const float* wih1f = (const float*)d_in[1];
  const float* whh1f = (const float*)d_in[2];
  const float* bih1f = (const float*)d_in[3];
  const float* bhh1f = (const float*)d_in[4];
  const float* wih1b = (const float*)d_in[5];
  const float* whh1b = (const float*)d_in[6];
  const float* bih1b = (const float*)d_in[7];
  const float* bhh1b = (const float*)d_in[8];
  const float* wih2f = (const float*)d_in[9];
  const float* whh2f = (const float*)d_in[10];
  const float* bih2f = (const float*)d_in[11];
  const float* bhh2f = (const float*)d_in[12];
  const float* wih2b = (const float*)d_in[13];
  const float* whh2b = (const float*)d_in[14];
  const float* bih2b = (const float*)d_in[15];
  const float* bhh2b = (const float*)d_in[16];
  const float* d1w = (const float*)d_in[17];
  const float* d1b = (const float*)d_in[18];
  const float* d2w = (const float*)d_in[19];
  const float* d2b = (const float*)d_in[20];
  const float* ow = (const float*)d_in[21];
  const float* ob = (const float*)d_in[22];
  float* out = (float*)d_out;
  char* wsb = (char*)d_ws;

  // adaptive batch slicing: per-slice bytes = rows*(352 + 96), rows = nb*1024
  const int cands[5] = {2, 4, 8, 16, 32};
  int nslice = 32;
  for (int i = 0; i < 5; ++i) {
    size_t rows = (size_t)(512 / cands[i]) * 1024;
    if (O_DATA + rows * 448 <= ws_size) { nslice = cands[i]; break; }
  }
  const int nb = 512 / nslice;
  int lognb = 0; while ((1 << lognb) < nb) ++lognb;
  const size_t rows = (size_t)nb * 1024;

  _Float16* wp1 = (_Float16*)(wsb + O_WP1);
  _Float16* wp2 = (_Float16*)(wsb + O_WP2);
  _Float16* h1  = (_Float16*)(wsb + O_DATA);          // becomes pre2 in place
  _Float16* h2  = (_Float16*)(wsb + O_DATA + rows * 352);

  pack_kernel<<<307, 256, 0, stream>>>(wih1f, whh1f, wih1b, whh1b,
                                       wih2f, wih2b, whh2f, whh2b,
                                       bih2f, bhh2f, bih2b, bhh2b, wsb);

  for (int s = 0; s < nslice; ++s) {
    const int b0 = s * nb;
    lstm1_kernel<<<dim3(nb, 2), 320, 0, stream>>>(x, bih1f, bhh1f, bih1b, bhh1b,
                                                  wp1, h1, b0, nb);
    pre2_kernel<<<nb * 16, 256, 0, stream>>>(h1, wsb);
    lstm2_kernel<<<dim3(nb, 2), 128, 0, stream>>>(h1, wp2, h2, nb);
    head_kernel<<<nb * 4, 256, 0, stream>>>(h2, d1w, d1b, d2w, d2b, ow, ob,
                                            out, b0, lognb);
  }
}